// Round 2
// 305.110 us; speedup vs baseline: 1.0760x; 1.0760x over previous
//
#include <hip/hip_runtime.h>
#include <cmath>

#define NJ 24

// clang vector type for nontemporal builtins (HIP's float4 is a class and
// is rejected by __builtin_nontemporal_load/store).
typedef float f4 __attribute__((ext_vector_type(4)));

__constant__ int PARENTS_c[NJ] = {-1, 0, 0, 0, 1, 2, 3, 4, 5, 6, 7, 8,
                                  9, 9, 9, 12, 13, 14, 16, 17, 18, 19, 20, 21};

// Root-to-joint ancestor paths (compile-time, from the fixed SMPL tree).
// Max depth 9. PLEN_c[j] = path length including j itself.
__constant__ signed char PATHS_c[NJ][9] = {
    {0, 0, 0, 0, 0, 0, 0, 0, 0},           // 0
    {0, 1, 0, 0, 0, 0, 0, 0, 0},           // 1
    {0, 2, 0, 0, 0, 0, 0, 0, 0},           // 2
    {0, 3, 0, 0, 0, 0, 0, 0, 0},           // 3
    {0, 1, 4, 0, 0, 0, 0, 0, 0},           // 4
    {0, 2, 5, 0, 0, 0, 0, 0, 0},           // 5
    {0, 3, 6, 0, 0, 0, 0, 0, 0},           // 6
    {0, 1, 4, 7, 0, 0, 0, 0, 0},           // 7
    {0, 2, 5, 8, 0, 0, 0, 0, 0},           // 8
    {0, 3, 6, 9, 0, 0, 0, 0, 0},           // 9
    {0, 1, 4, 7, 10, 0, 0, 0, 0},          // 10
    {0, 2, 5, 8, 11, 0, 0, 0, 0},          // 11
    {0, 3, 6, 9, 12, 0, 0, 0, 0},          // 12
    {0, 3, 6, 9, 13, 0, 0, 0, 0},          // 13
    {0, 3, 6, 9, 14, 0, 0, 0, 0},          // 14
    {0, 3, 6, 9, 12, 15, 0, 0, 0},         // 15
    {0, 3, 6, 9, 13, 16, 0, 0, 0},         // 16
    {0, 3, 6, 9, 14, 17, 0, 0, 0},         // 17
    {0, 3, 6, 9, 13, 16, 18, 0, 0},        // 18
    {0, 3, 6, 9, 14, 17, 19, 0, 0},        // 19
    {0, 3, 6, 9, 13, 16, 18, 20, 0},       // 20
    {0, 3, 6, 9, 14, 17, 19, 21, 0},       // 21
    {0, 3, 6, 9, 13, 16, 18, 20, 22},      // 22
    {0, 3, 6, 9, 14, 17, 19, 21, 23}};     // 23
__constant__ signed char PLEN_c[NJ] = {1, 2, 2, 2, 3, 3, 3, 4, 4, 4, 5, 5,
                                       5, 5, 5, 6, 6, 6, 7, 7, 8, 8, 9, 9};

// ---------------------------------------------------------------------------
// Kernel 1: partial reduction of J = J_regressor @ v_shaped and J0 (beta=0).
// grid = (24 joints, NPARTS chunks), block = 256.
// Jpart layout: [(j*NPARTS + p)*6 + c], c 0..2 = J, 3..5 = J0.
// ---------------------------------------------------------------------------
__global__ __launch_bounds__(256) void joints_partial_kernel(
    const float* __restrict__ shapedirs,   // (NV,3,10)
    const float* __restrict__ v_template,  // (NV,3)
    const float* __restrict__ J_reg,       // (24,NV)
    const float* __restrict__ beta,        // (10,)
    float* __restrict__ Jpart, int NVv) {
  const int j = blockIdx.x;
  const int part = blockIdx.y;
  const int nparts = gridDim.y;

  __shared__ float sbeta[10];
  if (threadIdx.x < 10) sbeta[threadIdx.x] = beta[threadIdx.x];
  __syncthreads();

  const int v0 = (NVv * part) / nparts;
  const int v1 = (NVv * (part + 1)) / nparts;

  float acc[6] = {0.f, 0.f, 0.f, 0.f, 0.f, 0.f};
  for (int v = v0 + (int)threadIdx.x; v < v1; v += blockDim.x) {
    float w = J_reg[(size_t)j * NVv + v];
#pragma unroll
    for (int c = 0; c < 3; ++c) {
      float vtc = v_template[(size_t)v * 3 + c];
      float vs = vtc;
      const float* sd = shapedirs + ((size_t)v * 3 + c) * 10;
#pragma unroll
      for (int k = 0; k < 10; ++k) vs = fmaf(sd[k], sbeta[k], vs);
      acc[c] = fmaf(w, vs, acc[c]);
      acc[3 + c] = fmaf(w, vtc, acc[3 + c]);
    }
  }

  // wave64 shuffle reduce, then across the 4 waves via LDS
#pragma unroll
  for (int c = 0; c < 6; ++c) {
    float x = acc[c];
#pragma unroll
    for (int off = 32; off > 0; off >>= 1) x += __shfl_down(x, off, 64);
    acc[c] = x;
  }
  __shared__ float wred[4][6];
  const int wave = threadIdx.x >> 6;
  const int lane = threadIdx.x & 63;
  if (lane == 0) {
#pragma unroll
    for (int c = 0; c < 6; ++c) wred[wave][c] = acc[c];
  }
  __syncthreads();
  if (threadIdx.x == 0) {
#pragma unroll
    for (int c = 0; c < 6; ++c) {
      float s = wred[0][c] + wred[1][c] + wred[2][c] + wred[3][c];
      Jpart[((size_t)j * nparts + part) * 6 + c] = s;
    }
  }
}

// ---------------------------------------------------------------------------
// Kernel 2: finish J reduction, Rodrigues, chain, pack, invert rest pose,
// compose A = pose @ inv(da). One block, 128 threads (2 waves), fp64.
//   wave 0 handles the posed chain, wave 1 the rest ('da') chain, so the
//   two Rodrigues + path-walk phases run on different SIMDs in parallel.
//   The old thread-0 serial chain (46 dependent fp64 affine muls) is
//   replaced by 24 parallel root-to-joint path walks (<= 9 muls deep).
// A_out: 24 x 12 floats (3x4 affine, row-major, col 3 = translation).
// ---------------------------------------------------------------------------
__device__ inline void rodrigues_local(double rx, double ry, double rz,
                                       double tx, double ty, double tz,
                                       double* L) {
  double th = sqrt(rx * rx + ry * ry + rz * rz) + 1e-8;
  double x = rx / th, y = ry / th, z = rz / th;
  double c = cos(th), s = sin(th), u = 1.0 - c;
  L[0] = c + u * x * x;  L[1] = u * x * y - s * z; L[2] = u * x * z + s * y; L[3] = tx;
  L[4] = u * x * y + s * z; L[5] = c + u * y * y;  L[6] = u * y * z - s * x; L[7] = ty;
  L[8] = u * x * z - s * y; L[9] = u * y * z + s * x; L[10] = c + u * z * z; L[11] = tz;
}

__device__ inline void affine_mul(const double* A, const double* B, double* C) {
#pragma unroll
  for (int r = 0; r < 3; ++r) {
#pragma unroll
    for (int cc = 0; cc < 3; ++cc)
      C[r * 4 + cc] = A[r * 4 + 0] * B[0 * 4 + cc] + A[r * 4 + 1] * B[1 * 4 + cc] +
                      A[r * 4 + 2] * B[2 * 4 + cc];
    C[r * 4 + 3] = A[r * 4 + 0] * B[3] + A[r * 4 + 1] * B[7] + A[r * 4 + 2] * B[11] +
                   A[r * 4 + 3];
  }
}

// Walk root->j multiplying local transforms; same left-to-right association
// as the old serial loop, so fp64 results are bit-identical.
__device__ inline void chain_walk(const double (*L)[12], int jj, double* M) {
  const signed char* path = PATHS_c[jj];
  const int len = PLEN_c[jj];
#pragma unroll
  for (int c = 0; c < 12; ++c) M[c] = L[path[0]][c];
  for (int k = 1; k < len; ++k) {
    double T[12];
    affine_mul(M, L[path[k]], T);
#pragma unroll
    for (int c = 0; c < 12; ++c) M[c] = T[c];
  }
}

__device__ inline void inv3(const double* m, double* o) {
  double det = m[0] * (m[4] * m[8] - m[5] * m[7]) -
               m[1] * (m[3] * m[8] - m[5] * m[6]) +
               m[2] * (m[3] * m[7] - m[4] * m[6]);
  double id = 1.0 / det;
  o[0] = (m[4] * m[8] - m[5] * m[7]) * id;
  o[1] = (m[2] * m[7] - m[1] * m[8]) * id;
  o[2] = (m[1] * m[5] - m[2] * m[4]) * id;
  o[3] = (m[5] * m[6] - m[3] * m[8]) * id;
  o[4] = (m[0] * m[8] - m[2] * m[6]) * id;
  o[5] = (m[2] * m[3] - m[0] * m[5]) * id;
  o[6] = (m[3] * m[7] - m[4] * m[6]) * id;
  o[7] = (m[1] * m[6] - m[0] * m[7]) * id;
  o[8] = (m[0] * m[4] - m[1] * m[3]) * id;
}

__global__ __launch_bounds__(128) void transforms_kernel(
    const float* __restrict__ theta,     // (24,3)
    const float* __restrict__ da_theta,  // (24,3)
    const float* __restrict__ Jpart,     // (24, nparts, 6)
    int nparts,
    float* __restrict__ A_out) {         // (24,12)
  __shared__ double J[NJ][3], J0[NJ][3];
  __shared__ double Lp[NJ][12], Ld[NJ][12], Gp[NJ][12], Gd[NJ][12];
  const int t = threadIdx.x;

  // Phase 1: finish J / J0 reduction (wave 0, lanes 0..23)
  if (t < NJ) {
#pragma unroll
    for (int c = 0; c < 3; ++c) {
      double s = 0.0, s0 = 0.0;
      for (int p = 0; p < nparts; ++p) {
        s += (double)Jpart[(t * nparts + p) * 6 + c];
        s0 += (double)Jpart[(t * nparts + p) * 6 + 3 + c];
      }
      J[t][c] = s;
      J0[t][c] = s0;
    }
  }
  __syncthreads();

  // Phase 2: Rodrigues — pose on wave 0, da on wave 1 (parallel SIMDs).
  if (t < NJ) {
    const int j = t;
    int par = PARENTS_c[j];
    double jx = J[j][0], jy = J[j][1], jz = J[j][2];
    if (par >= 0) { jx -= J[par][0]; jy -= J[par][1]; jz -= J[par][2]; }
    rodrigues_local(theta[j * 3], theta[j * 3 + 1], theta[j * 3 + 2], jx, jy, jz, Lp[j]);
  } else if (t >= 64 && t < 64 + NJ) {
    const int j = t - 64;
    int par = PARENTS_c[j];
    double j0x = J0[j][0], j0y = J0[j][1], j0z = J0[j][2];
    if (par >= 0) { j0x -= J0[par][0]; j0y -= J0[par][1]; j0z -= J0[par][2]; }
    rodrigues_local(da_theta[j * 3], da_theta[j * 3 + 1], da_theta[j * 3 + 2],
                    j0x, j0y, j0z, Ld[j]);
  }
  __syncthreads();

  // Phase 3: parallel root->joint path walks (depth <= 9, vs 46 serial).
  if (t < NJ) {
    double M[12];
    chain_walk(Lp, t, M);
#pragma unroll
    for (int c = 0; c < 12; ++c) Gp[t][c] = M[c];
  } else if (t >= 64 && t < 64 + NJ) {
    const int j = t - 64;
    double M[12];
    chain_walk(Ld, j, M);
#pragma unroll
    for (int c = 0; c < 12; ++c) Gd[j][c] = M[c];
  }
  __syncthreads();

  // Phase 4: pack, invert rest pose, compose A = pose o inv(da).
  if (t < NJ) {
    const int j = t;
    double P[12], D[12];
#pragma unroll
    for (int r = 0; r < 3; ++r) {
      double tp = Gp[j][r * 4 + 0] * J[j][0] + Gp[j][r * 4 + 1] * J[j][1] +
                  Gp[j][r * 4 + 2] * J[j][2];
      P[r * 4 + 0] = Gp[j][r * 4 + 0];
      P[r * 4 + 1] = Gp[j][r * 4 + 1];
      P[r * 4 + 2] = Gp[j][r * 4 + 2];
      P[r * 4 + 3] = Gp[j][r * 4 + 3] - tp;
      double td = Gd[j][r * 4 + 0] * J0[j][0] + Gd[j][r * 4 + 1] * J0[j][1] +
                  Gd[j][r * 4 + 2] * J0[j][2];
      D[r * 4 + 0] = Gd[j][r * 4 + 0];
      D[r * 4 + 1] = Gd[j][r * 4 + 1];
      D[r * 4 + 2] = Gd[j][r * 4 + 2];
      D[r * 4 + 3] = Gd[j][r * 4 + 3] - td;
    }
    // affine inverse of D
    double m[9] = {D[0], D[1], D[2], D[4], D[5], D[6], D[8], D[9], D[10]};
    double mi[9];
    inv3(m, mi);
    double it[3];
#pragma unroll
    for (int r = 0; r < 3; ++r)
      it[r] = -(mi[r * 3 + 0] * D[3] + mi[r * 3 + 1] * D[7] + mi[r * 3 + 2] * D[11]);
    // A = P o Dinv
#pragma unroll
    for (int r = 0; r < 3; ++r) {
#pragma unroll
      for (int cc = 0; cc < 3; ++cc)
        A_out[j * 12 + r * 4 + cc] =
            (float)(P[r * 4 + 0] * mi[0 * 3 + cc] + P[r * 4 + 1] * mi[1 * 3 + cc] +
                    P[r * 4 + 2] * mi[2 * 3 + cc]);
      A_out[j * 12 + r * 4 + 3] =
          (float)(P[r * 4 + 0] * it[0] + P[r * 4 + 1] * it[1] +
                  P[r * 4 + 2] * it[2] + P[r * 4 + 3]);
    }
  }
}

// ---------------------------------------------------------------------------
// Kernel 3: the memory-bound LBS blend. One thread = 4 points (16B loads).
// Streaming arrays use non-temporal hints (touched exactly once).
// ---------------------------------------------------------------------------
__global__ __launch_bounds__(256) void lbs_kernel(
    const float* __restrict__ points,   // (3,N)
    const float* __restrict__ weights,  // (24,N)
    const float* __restrict__ A,        // (24,12)
    float* __restrict__ out,            // (3,N)
    int N) {
  __shared__ float sA[NJ * 12];
  for (int i = threadIdx.x; i < NJ * 12; i += blockDim.x) sA[i] = A[i];
  __syncthreads();

  const int tid = blockIdx.x * blockDim.x + threadIdx.x;
  const int n4 = tid * 4;
  if (n4 >= N) return;
  const size_t Ns = (size_t)N;

  if (n4 + 4 <= N) {
    f4 px = __builtin_nontemporal_load((const f4*)(points + n4));
    f4 py = __builtin_nontemporal_load((const f4*)(points + Ns + n4));
    f4 pz = __builtin_nontemporal_load((const f4*)(points + 2 * Ns + n4));

    f4 T[12];
#pragma unroll
    for (int r = 0; r < 12; ++r) T[r] = (f4)(0.f);

#pragma unroll
    for (int jj = 0; jj < NJ; ++jj) {
      f4 w = __builtin_nontemporal_load((const f4*)(weights + (size_t)jj * Ns + n4));
#pragma unroll
      for (int r = 0; r < 12; ++r) {
        float a = sA[jj * 12 + r];
        T[r].x = fmaf(w.x, a, T[r].x);
        T[r].y = fmaf(w.y, a, T[r].y);
        T[r].z = fmaf(w.z, a, T[r].z);
        T[r].w = fmaf(w.w, a, T[r].w);
      }
    }

    f4 ox, oy, oz;
    ox.x = fmaf(T[0].x, px.x, fmaf(T[1].x, py.x, fmaf(T[2].x, pz.x, T[3].x)));
    ox.y = fmaf(T[0].y, px.y, fmaf(T[1].y, py.y, fmaf(T[2].y, pz.y, T[3].y)));
    ox.z = fmaf(T[0].z, px.z, fmaf(T[1].z, py.z, fmaf(T[2].z, pz.z, T[3].z)));
    ox.w = fmaf(T[0].w, px.w, fmaf(T[1].w, py.w, fmaf(T[2].w, pz.w, T[3].w)));
    oy.x = fmaf(T[4].x, px.x, fmaf(T[5].x, py.x, fmaf(T[6].x, pz.x, T[7].x)));
    oy.y = fmaf(T[4].y, px.y, fmaf(T[5].y, py.y, fmaf(T[6].y, pz.y, T[7].y)));
    oy.z = fmaf(T[4].z, px.z, fmaf(T[6 - 1].z, py.z, fmaf(T[6].z, pz.z, T[7].z)));
    oy.w = fmaf(T[4].w, px.w, fmaf(T[5].w, py.w, fmaf(T[6].w, pz.w, T[7].w)));
    oz.x = fmaf(T[8].x, px.x, fmaf(T[9].x, py.x, fmaf(T[10].x, pz.x, T[11].x)));
    oz.y = fmaf(T[8].y, px.y, fmaf(T[9].y, py.y, fmaf(T[10].y, pz.y, T[11].y)));
    oz.z = fmaf(T[8].z, px.z, fmaf(T[9].z, py.z, fmaf(T[10].z, pz.z, T[11].z)));
    oz.w = fmaf(T[8].w, px.w, fmaf(T[9].w, py.w, fmaf(T[10].w, pz.w, T[11].w)));

    __builtin_nontemporal_store(ox, (f4*)(out + n4));
    __builtin_nontemporal_store(oy, (f4*)(out + Ns + n4));
    __builtin_nontemporal_store(oz, (f4*)(out + 2 * Ns + n4));
  } else {
    for (int n = n4; n < N; ++n) {
      float X = points[n], Y = points[Ns + n], Z = points[2 * Ns + n];
      float T[12];
#pragma unroll
      for (int r = 0; r < 12; ++r) T[r] = 0.f;
      for (int jj = 0; jj < NJ; ++jj) {
        float w = weights[(size_t)jj * Ns + n];
#pragma unroll
        for (int r = 0; r < 12; ++r) T[r] = fmaf(w, sA[jj * 12 + r], T[r]);
      }
      out[n] = fmaf(T[0], X, fmaf(T[1], Y, fmaf(T[2], Z, T[3])));
      out[Ns + n] = fmaf(T[4], X, fmaf(T[5], Y, fmaf(T[6], Z, T[7])));
      out[2 * Ns + n] = fmaf(T[8], X, fmaf(T[9], Y, fmaf(T[10], Z, T[11])));
    }
  }
}

extern "C" void kernel_launch(void* const* d_in, const int* in_sizes, int n_in,
                              void* d_out, int out_size, void* d_ws, size_t ws_size,
                              hipStream_t stream) {
  const float* points = (const float*)d_in[0];
  const float* weights = (const float*)d_in[1];
  const float* beta = (const float*)d_in[2];
  const float* theta = (const float*)d_in[3];
  const float* da_theta = (const float*)d_in[4];
  const float* shapedirs = (const float*)d_in[5];
  const float* v_template = (const float*)d_in[6];
  const float* J_regressor = (const float*)d_in[7];

  const int N = in_sizes[0] / 3;
  const int NVv = in_sizes[6] / 3;
  const int NPARTS = 16;  // 24*16 = 384 blocks -> covers all 256 CUs

  float* ws = (float*)d_ws;
  float* A = ws;             // 288 floats
  float* Jpart = ws + 512;   // 24*NPARTS*6 floats

  dim3 gA(NJ, NPARTS);
  joints_partial_kernel<<<gA, 256, 0, stream>>>(shapedirs, v_template, J_regressor,
                                                beta, Jpart, NVv);
  transforms_kernel<<<1, 128, 0, stream>>>(theta, da_theta, Jpart, NPARTS, A);

  const int threads_total = (N + 3) / 4;
  const int blocks = (threads_total + 255) / 256;
  lbs_kernel<<<blocks, 256, 0, stream>>>(points, weights, A, (float*)d_out, N);
}